// Round 3
// baseline (113.818 us; speedup 1.0000x reference)
//
#include <hip/hip_runtime.h>

// RLS step, wave-autonomous version: ONE WAVE per batch row, no LDS, no
// barriers (so the compiler never emits s_waitcnt vmcnt(0)+s_barrier drains).
// Each wave processes ROWS consecutive rows with double-buffered register
// prefetch: row i+1's 16KB P tile is issued before row i's compute, keeping
// the memory pipe busy across the whole wave lifetime.
//
// Lane ownership (per row): lane l holds float4 flat index k*64+l, k=0..15
//   -> row(k) = 4k + (l>>4), cols 4*(l&15)..+3.  Coalesced 1KB/instr.
// Reductions (all intra-wave):
//   Px[row]   : butterfly xor 1,2,4,8 over the 16 lanes sharing l>>4
//   xP[col]   : butterfly xor 16,32 over the 4 groups sharing l&15
//   denom,y^  : full-wave butterfly (all lanes keep the scalar)
//   Px[l]     : 16 static bpermute + select (transpose to lane-major)

constexpr int T    = 64;
constexpr int ROWS = 4;   // rows per wave
constexpr int WPB  = 4;   // waves per block (256 threads)

__global__ __launch_bounds__(256) void rls_step(
    const float* __restrict__ x,       // (B,64)
    const float* __restrict__ d,       // (B,)
    const float* __restrict__ w_prev,  // (B,64)
    const float* __restrict__ P_prev,  // (B,64,64)
    const float* __restrict__ ffp,     // (1,)
    float* __restrict__ w_next,       // (B,64)
    float* __restrict__ P_next,       // (B,64,64)
    float* __restrict__ y_hat,        // (B,)
    int B)
{
    const int t  = threadIdx.x;
    const int l  = t & 63;
    const int gw = blockIdx.x * WPB + (t >> 6);
    const int b0 = gw * ROWS;
    if (b0 >= B) return;

    const int g   = l >> 4;    // row-group 0..3
    const int s16 = l & 15;    // col-group 0..15
    const int c0  = s16 * 4;   // first owned column

    const float lam     = fminf(fmaxf(ffp[0], 1.0e-4f), 0.9999f);
    const float inv_lam = 1.0f / lam;

    float4 pA[16], pB[16];
    float  xvA, wvA, dbA;  float4 xcA;
    float  xvB, wvB, dbB;  float4 xcB;

    auto LOADROW = [&](float4 (&p)[16], float& xv, float& wv, float4& xc,
                       float& db, int bi) {
        const float4* __restrict__ Pv =
            reinterpret_cast<const float4*>(P_prev) + (size_t)bi * (T * T / 4);
        #pragma unroll
        for (int k = 0; k < 16; ++k) p[k] = Pv[k * 64 + l];
        xv = x[(size_t)bi * T + l];
        wv = w_prev[(size_t)bi * T + l];
        xc = *reinterpret_cast<const float4*>(x + (size_t)bi * T + c0);
        db = d[bi];
    };

    auto DOROW = [&](float4 (&p)[16], float xv, float wv, float4 xc,
                     float db, int bi) {
        // x at this lane's 16 rows (bpermute from the lane-major copy).
        float xi[16];
        #pragma unroll
        for (int k = 0; k < 16; ++k) xi[k] = __shfl(xv, 4 * k + g);

        // Row partials over owned cols; accumulate denom & xP partials.
        float r[16];
        float dp = 0.0f, s0 = 0.0f, s1 = 0.0f, s2 = 0.0f, s3 = 0.0f;
        #pragma unroll
        for (int k = 0; k < 16; ++k) {
            r[k] = p[k].x * xc.x + p[k].y * xc.y + p[k].z * xc.z + p[k].w * xc.w;
            dp += xi[k] * r[k];
            s0 += xi[k] * p[k].x;
            s1 += xi[k] * p[k].y;
            s2 += xi[k] * p[k].z;
            s3 += xi[k] * p[k].w;
        }

        // denom = lam + x.Px  (full-wave butterfly on the partials)
        dp += __shfl_xor(dp, 1);  dp += __shfl_xor(dp, 2);  dp += __shfl_xor(dp, 4);
        dp += __shfl_xor(dp, 8);  dp += __shfl_xor(dp, 16); dp += __shfl_xor(dp, 32);
        const float inv_den = 1.0f / (lam + dp);

        // xP at owned cols: reduce the 4 row-groups.
        s0 += __shfl_xor(s0, 16); s0 += __shfl_xor(s0, 32);
        s1 += __shfl_xor(s1, 16); s1 += __shfl_xor(s1, 32);
        s2 += __shfl_xor(s2, 16); s2 += __shfl_xor(s2, 32);
        s3 += __shfl_xor(s3, 16); s3 += __shfl_xor(s3, 32);

        // y_hat / error (full-wave butterfly, all lanes keep).
        float yp = wv * xv;
        yp += __shfl_xor(yp, 1);  yp += __shfl_xor(yp, 2);  yp += __shfl_xor(yp, 4);
        yp += __shfl_xor(yp, 8);  yp += __shfl_xor(yp, 16); yp += __shfl_xor(yp, 32);
        const float err = db - yp;

        // Px row sums: butterfly over the 16 lanes sharing g; all lanes keep.
        #pragma unroll
        for (int k = 0; k < 16; ++k) {
            r[k] += __shfl_xor(r[k], 1); r[k] += __shfl_xor(r[k], 2);
            r[k] += __shfl_xor(r[k], 4); r[k] += __shfl_xor(r[k], 8);
        }

        // Transpose Px to lane-major: Px[l] on lane l (static k, no scratch).
        float Pxl = 0.0f;
        const int srcl = (l & 3) << 4;   // a lane in row-group l&3
        #pragma unroll
        for (int k = 0; k < 16; ++k) {
            const float tk = __shfl(r[k], srcl);   // Px[4k + (l&3)]
            if ((l >> 2) == k) Pxl = tk;
        }

        // w_next + y_hat
        w_next[(size_t)bi * T + l] = wv + Pxl * inv_den * err;
        if (l == 0) y_hat[bi] = yp;

        // P_next = (P - g * xP) / lam from live registers.
        float4* __restrict__ Pnv =
            reinterpret_cast<float4*>(P_next) + (size_t)bi * (T * T / 4);
        #pragma unroll
        for (int k = 0; k < 16; ++k) {
            const float gk = r[k] * inv_den;
            float4 o;
            o.x = (p[k].x - gk * s0) * inv_lam;
            o.y = (p[k].y - gk * s1) * inv_lam;
            o.z = (p[k].z - gk * s2) * inv_lam;
            o.w = (p[k].w - gk * s3) * inv_lam;
            Pnv[k * 64 + l] = o;
        }
    };

    // Software pipeline: prefetch one row ahead in the other register buffer.
    LOADROW(pA, xvA, wvA, xcA, dbA, b0 + 0);
    LOADROW(pB, xvB, wvB, xcB, dbB, b0 + 1);
    DOROW  (pA, xvA, wvA, xcA, dbA, b0 + 0);
    LOADROW(pA, xvA, wvA, xcA, dbA, b0 + 2);
    DOROW  (pB, xvB, wvB, xcB, dbB, b0 + 1);
    LOADROW(pB, xvB, wvB, xcB, dbB, b0 + 3);
    DOROW  (pA, xvA, wvA, xcA, dbA, b0 + 2);
    DOROW  (pB, xvB, wvB, xcB, dbB, b0 + 3);
}

extern "C" void kernel_launch(void* const* d_in, const int* in_sizes, int n_in,
                              void* d_out, int out_size, void* d_ws, size_t ws_size,
                              hipStream_t stream) {
    const float* x      = (const float*)d_in[0];
    const float* d      = (const float*)d_in[1];
    const float* w_prev = (const float*)d_in[2];
    const float* P_prev = (const float*)d_in[3];
    const float* ffp    = (const float*)d_in[4];

    const int B = in_sizes[1];   // d has B elements

    float* out    = (float*)d_out;
    float* w_next = out;
    float* P_next = out + (size_t)B * T;
    float* y_hat  = out + (size_t)B * T + (size_t)B * T * T;

    const int rows_per_block = WPB * ROWS;             // 16
    const int grid = (B + rows_per_block - 1) / rows_per_block;

    rls_step<<<grid, 256, 0, stream>>>(x, d, w_prev, P_prev, ffp,
                                       w_next, P_next, y_hat, B);
}

// Round 4
// 100.625 us; speedup vs baseline: 1.1311x; 1.1311x over previous
//
#include <hip/hip_runtime.h>

// RLS step, low-VGPR single-barrier version.
// One 256-thread block per batch row b. Wave w (0..3) owns P rows
// 16w..16w+15: lane l, j=0..3 -> row 16w+4j+(l>>4), cols 4*(l&15)..+3.
// Register footprint for P is 4 float4 = 16 VGPR; __launch_bounds__(256,8)
// caps the kernel at 64 VGPR -> 8 blocks (32 waves) per CU for max
// memory-latency hiding. Exactly ONE __syncthreads.

constexpr int T = 64;

__global__ __launch_bounds__(256, 8) void rls_step(
    const float* __restrict__ x,       // (B,64)
    const float* __restrict__ d,       // (B,)
    const float* __restrict__ w_prev,  // (B,64)
    const float* __restrict__ P_prev,  // (B,64,64)
    const float* __restrict__ ffp,     // (1,)
    float* __restrict__ w_next,        // (B,64)
    float* __restrict__ P_next,        // (B,64,64)
    float* __restrict__ y_hat)         // (B,)
{
    const int b = blockIdx.x;
    const int t = threadIdx.x;
    const int w = t >> 6;        // wave 0..3
    const int l = t & 63;
    const int s16 = l & 15;      // col group
    const int c0  = s16 * 4;     // first owned column

    __shared__ float4 xPw[4][16];   // per-wave xP partials (64 cols as 16 float4)
    __shared__ float  denw[4];      // per-wave denom partials
    __shared__ float  Px_s[T];      // Px, row-indexed (for w_next transpose)

    const float lam     = fminf(fmaxf(ffp[0], 1.0e-4f), 0.9999f);
    const float inv_lam = 1.0f / lam;
    const float db      = d[b];     // uniform -> scalar load

    const float4* __restrict__ Pv =
        reinterpret_cast<const float4*>(P_prev) + (size_t)b * (T * T / 4);
    float4* __restrict__ Pnv =
        reinterpret_cast<float4*>(P_next) + (size_t)b * (T * T / 4);

    // This wave's 16 rows of P: flat float4 index 256w + 64j + l (coalesced).
    float4 p0 = Pv[256 * w +   0 + l];
    float4 p1 = Pv[256 * w +  64 + l];
    float4 p2 = Pv[256 * w + 128 + l];
    float4 p3 = Pv[256 * w + 192 + l];

    const float  xv = x[(size_t)b * T + l];
    const float  wv = w_prev[(size_t)b * T + l];
    const float4 xc = *reinterpret_cast<const float4*>(x + (size_t)b * T + c0);

    // x at this lane's 4 rows (row = 16w + 4j + (l>>4)).
    const int rbase = 16 * w + (l >> 4);
    const float xi0 = __shfl(xv, rbase + 0);
    const float xi1 = __shfl(xv, rbase + 4);
    const float xi2 = __shfl(xv, rbase + 8);
    const float xi3 = __shfl(xv, rbase + 12);

    // Row partial dots over owned cols.
    float r0 = p0.x * xc.x + p0.y * xc.y + p0.z * xc.z + p0.w * xc.w;
    float r1 = p1.x * xc.x + p1.y * xc.y + p1.z * xc.z + p1.w * xc.w;
    float r2 = p2.x * xc.x + p2.y * xc.y + p2.z * xc.z + p2.w * xc.w;
    float r3 = p3.x * xc.x + p3.y * xc.y + p3.z * xc.z + p3.w * xc.w;

    // denom partial (this wave's rows' contribution to x^T P x).
    float dp = xi0 * r0 + xi1 * r1 + xi2 * r2 + xi3 * r3;
    dp += __shfl_xor(dp, 1);  dp += __shfl_xor(dp, 2);  dp += __shfl_xor(dp, 4);
    dp += __shfl_xor(dp, 8);  dp += __shfl_xor(dp, 16); dp += __shfl_xor(dp, 32);
    if (l == 0) denw[w] = dp;

    // xP partials at owned cols: sum over this wave's 16 rows.
    float s0 = xi0 * p0.x + xi1 * p1.x + xi2 * p2.x + xi3 * p3.x;
    float s1 = xi0 * p0.y + xi1 * p1.y + xi2 * p2.y + xi3 * p3.y;
    float s2 = xi0 * p0.z + xi1 * p1.z + xi2 * p2.z + xi3 * p3.z;
    float s3 = xi0 * p0.w + xi1 * p1.w + xi2 * p2.w + xi3 * p3.w;
    s0 += __shfl_xor(s0, 16); s0 += __shfl_xor(s0, 32);
    s1 += __shfl_xor(s1, 16); s1 += __shfl_xor(s1, 32);
    s2 += __shfl_xor(s2, 16); s2 += __shfl_xor(s2, 32);
    s3 += __shfl_xor(s3, 16); s3 += __shfl_xor(s3, 32);
    if (l < 16) xPw[w][l] = make_float4(s0, s1, s2, s3);

    // y_hat (redundant in every wave; all lanes keep it).
    float yp = wv * xv;
    yp += __shfl_xor(yp, 1);  yp += __shfl_xor(yp, 2);  yp += __shfl_xor(yp, 4);
    yp += __shfl_xor(yp, 8);  yp += __shfl_xor(yp, 16); yp += __shfl_xor(yp, 32);
    const float err = db - yp;

    // Px: reduce over the 16 lanes sharing a row; all lanes keep the sums.
    r0 += __shfl_xor(r0, 1); r0 += __shfl_xor(r0, 2); r0 += __shfl_xor(r0, 4); r0 += __shfl_xor(r0, 8);
    r1 += __shfl_xor(r1, 1); r1 += __shfl_xor(r1, 2); r1 += __shfl_xor(r1, 4); r1 += __shfl_xor(r1, 8);
    r2 += __shfl_xor(r2, 1); r2 += __shfl_xor(r2, 2); r2 += __shfl_xor(r2, 4); r2 += __shfl_xor(r2, 8);
    r3 += __shfl_xor(r3, 1); r3 += __shfl_xor(r3, 2); r3 += __shfl_xor(r3, 4); r3 += __shfl_xor(r3, 8);
    if (s16 == 0) {
        Px_s[rbase + 0]  = r0;
        Px_s[rbase + 4]  = r1;
        Px_s[rbase + 8]  = r2;
        Px_s[rbase + 12] = r3;
    }

    __syncthreads();   // the only barrier

    const float inv_den = 1.0f / (lam + denw[0] + denw[1] + denw[2] + denw[3]);

    // Total xP at this lane's 4 cols.
    const float4 q0 = xPw[0][s16], q1 = xPw[1][s16];
    const float4 q2 = xPw[2][s16], q3 = xPw[3][s16];
    const float xq0 = q0.x + q1.x + q2.x + q3.x;
    const float xq1 = q0.y + q1.y + q2.y + q3.y;
    const float xq2 = q0.z + q1.z + q2.z + q3.z;
    const float xq3 = q0.w + q1.w + q2.w + q3.w;

    if (w == 0) {
        w_next[(size_t)b * T + l] = wv + Px_s[l] * inv_den * err;
        if (l == 0) y_hat[b] = yp;
    }

    // P_next = (P - g * xP) / lam from live registers.
    const float g0 = r0 * inv_den;
    const float g1 = r1 * inv_den;
    const float g2 = r2 * inv_den;
    const float g3 = r3 * inv_den;
    float4 o;
    o.x = (p0.x - g0 * xq0) * inv_lam;
    o.y = (p0.y - g0 * xq1) * inv_lam;
    o.z = (p0.z - g0 * xq2) * inv_lam;
    o.w = (p0.w - g0 * xq3) * inv_lam;
    Pnv[256 * w +   0 + l] = o;
    o.x = (p1.x - g1 * xq0) * inv_lam;
    o.y = (p1.y - g1 * xq1) * inv_lam;
    o.z = (p1.z - g1 * xq2) * inv_lam;
    o.w = (p1.w - g1 * xq3) * inv_lam;
    Pnv[256 * w +  64 + l] = o;
    o.x = (p2.x - g2 * xq0) * inv_lam;
    o.y = (p2.y - g2 * xq1) * inv_lam;
    o.z = (p2.z - g2 * xq2) * inv_lam;
    o.w = (p2.w - g2 * xq3) * inv_lam;
    Pnv[256 * w + 128 + l] = o;
    o.x = (p3.x - g3 * xq0) * inv_lam;
    o.y = (p3.y - g3 * xq1) * inv_lam;
    o.z = (p3.z - g3 * xq2) * inv_lam;
    o.w = (p3.w - g3 * xq3) * inv_lam;
    Pnv[256 * w + 192 + l] = o;
}

extern "C" void kernel_launch(void* const* d_in, const int* in_sizes, int n_in,
                              void* d_out, int out_size, void* d_ws, size_t ws_size,
                              hipStream_t stream) {
    const float* x      = (const float*)d_in[0];
    const float* d      = (const float*)d_in[1];
    const float* w_prev = (const float*)d_in[2];
    const float* P_prev = (const float*)d_in[3];
    const float* ffp    = (const float*)d_in[4];

    const int B = in_sizes[1];   // d has B elements

    float* out    = (float*)d_out;
    float* w_next = out;
    float* P_next = out + (size_t)B * T;
    float* y_hat  = out + (size_t)B * T + (size_t)B * T * T;

    rls_step<<<B, 256, 0, stream>>>(x, d, w_prev, P_prev, ffp,
                                    w_next, P_next, y_hat);
}

// Round 6
// 90.125 us; speedup vs baseline: 1.2629x; 1.1165x over previous
//
#include <hip/hip_runtime.h>

// RLS step, low-VGPR single-barrier version + NON-TEMPORAL P streams.
// One 256-thread block per batch row b. Wave w (0..3) owns P rows
// 16w..16w+15: lane l, j=0..3 -> row 16w+4j+(l>>4), cols 4*(l&15)..+3.
// P_prev/P_next are touched exactly once -> nt loads/stores (no L2/L3
// allocate) to cut cache churn on the 540 MB streaming traffic.
// NOTE: __builtin_nontemporal_* requires native vector types, not
// HIP_vector_type -> use ext_vector_type(4).

constexpr int T = 64;

typedef float fx4 __attribute__((ext_vector_type(4)));

__global__ __launch_bounds__(256, 8) void rls_step(
    const float* __restrict__ x,       // (B,64)
    const float* __restrict__ d,       // (B,)
    const float* __restrict__ w_prev,  // (B,64)
    const float* __restrict__ P_prev,  // (B,64,64)
    const float* __restrict__ ffp,     // (1,)
    float* __restrict__ w_next,        // (B,64)
    float* __restrict__ P_next,        // (B,64,64)
    float* __restrict__ y_hat)         // (B,)
{
    const int b = blockIdx.x;
    const int t = threadIdx.x;
    const int w = t >> 6;        // wave 0..3
    const int l = t & 63;
    const int s16 = l & 15;      // col group
    const int c0  = s16 * 4;     // first owned column

    __shared__ float4 xPw[4][16];   // per-wave xP partials (64 cols as 16 float4)
    __shared__ float  denw[4];      // per-wave denom partials
    __shared__ float  Px_s[T];      // Px, row-indexed (for w_next transpose)

    const float lam     = fminf(fmaxf(ffp[0], 1.0e-4f), 0.9999f);
    const float inv_lam = 1.0f / lam;
    const float db      = d[b];     // uniform -> scalar load

    const fx4* __restrict__ Pv =
        reinterpret_cast<const fx4*>(P_prev) + (size_t)b * (T * T / 4);
    fx4* __restrict__ Pnv =
        reinterpret_cast<fx4*>(P_next) + (size_t)b * (T * T / 4);

    // This wave's 16 rows of P: flat float4 index 256w + 64j + l (coalesced),
    // streamed with nt (no cache allocate).
    fx4 p0 = __builtin_nontemporal_load(&Pv[256 * w +   0 + l]);
    fx4 p1 = __builtin_nontemporal_load(&Pv[256 * w +  64 + l]);
    fx4 p2 = __builtin_nontemporal_load(&Pv[256 * w + 128 + l]);
    fx4 p3 = __builtin_nontemporal_load(&Pv[256 * w + 192 + l]);

    const float  xv = x[(size_t)b * T + l];
    const float  wv = w_prev[(size_t)b * T + l];
    const float4 xc = *reinterpret_cast<const float4*>(x + (size_t)b * T + c0);

    // x at this lane's 4 rows (row = 16w + 4j + (l>>4)).
    const int rbase = 16 * w + (l >> 4);
    const float xi0 = __shfl(xv, rbase + 0);
    const float xi1 = __shfl(xv, rbase + 4);
    const float xi2 = __shfl(xv, rbase + 8);
    const float xi3 = __shfl(xv, rbase + 12);

    // Row partial dots over owned cols.
    float r0 = p0.x * xc.x + p0.y * xc.y + p0.z * xc.z + p0.w * xc.w;
    float r1 = p1.x * xc.x + p1.y * xc.y + p1.z * xc.z + p1.w * xc.w;
    float r2 = p2.x * xc.x + p2.y * xc.y + p2.z * xc.z + p2.w * xc.w;
    float r3 = p3.x * xc.x + p3.y * xc.y + p3.z * xc.z + p3.w * xc.w;

    // denom partial (this wave's rows' contribution to x^T P x).
    float dp = xi0 * r0 + xi1 * r1 + xi2 * r2 + xi3 * r3;
    dp += __shfl_xor(dp, 1);  dp += __shfl_xor(dp, 2);  dp += __shfl_xor(dp, 4);
    dp += __shfl_xor(dp, 8);  dp += __shfl_xor(dp, 16); dp += __shfl_xor(dp, 32);
    if (l == 0) denw[w] = dp;

    // xP partials at owned cols: sum over this wave's 16 rows.
    float s0 = xi0 * p0.x + xi1 * p1.x + xi2 * p2.x + xi3 * p3.x;
    float s1 = xi0 * p0.y + xi1 * p1.y + xi2 * p2.y + xi3 * p3.y;
    float s2 = xi0 * p0.z + xi1 * p1.z + xi2 * p2.z + xi3 * p3.z;
    float s3 = xi0 * p0.w + xi1 * p1.w + xi2 * p2.w + xi3 * p3.w;
    s0 += __shfl_xor(s0, 16); s0 += __shfl_xor(s0, 32);
    s1 += __shfl_xor(s1, 16); s1 += __shfl_xor(s1, 32);
    s2 += __shfl_xor(s2, 16); s2 += __shfl_xor(s2, 32);
    s3 += __shfl_xor(s3, 16); s3 += __shfl_xor(s3, 32);
    if (l < 16) xPw[w][l] = make_float4(s0, s1, s2, s3);

    // y_hat (redundant in every wave; all lanes keep it).
    float yp = wv * xv;
    yp += __shfl_xor(yp, 1);  yp += __shfl_xor(yp, 2);  yp += __shfl_xor(yp, 4);
    yp += __shfl_xor(yp, 8);  yp += __shfl_xor(yp, 16); yp += __shfl_xor(yp, 32);
    const float err = db - yp;

    // Px: reduce over the 16 lanes sharing a row; all lanes keep the sums.
    r0 += __shfl_xor(r0, 1); r0 += __shfl_xor(r0, 2); r0 += __shfl_xor(r0, 4); r0 += __shfl_xor(r0, 8);
    r1 += __shfl_xor(r1, 1); r1 += __shfl_xor(r1, 2); r1 += __shfl_xor(r1, 4); r1 += __shfl_xor(r1, 8);
    r2 += __shfl_xor(r2, 1); r2 += __shfl_xor(r2, 2); r2 += __shfl_xor(r2, 4); r2 += __shfl_xor(r2, 8);
    r3 += __shfl_xor(r3, 1); r3 += __shfl_xor(r3, 2); r3 += __shfl_xor(r3, 4); r3 += __shfl_xor(r3, 8);
    if (s16 == 0) {
        Px_s[rbase + 0]  = r0;
        Px_s[rbase + 4]  = r1;
        Px_s[rbase + 8]  = r2;
        Px_s[rbase + 12] = r3;
    }

    __syncthreads();   // the only barrier

    const float inv_den = 1.0f / (lam + denw[0] + denw[1] + denw[2] + denw[3]);

    // Total xP at this lane's 4 cols.
    const float4 q0 = xPw[0][s16], q1 = xPw[1][s16];
    const float4 q2 = xPw[2][s16], q3 = xPw[3][s16];
    const float xq0 = q0.x + q1.x + q2.x + q3.x;
    const float xq1 = q0.y + q1.y + q2.y + q3.y;
    const float xq2 = q0.z + q1.z + q2.z + q3.z;
    const float xq3 = q0.w + q1.w + q2.w + q3.w;

    if (w == 0) {
        w_next[(size_t)b * T + l] = wv + Px_s[l] * inv_den * err;
        if (l == 0) y_hat[b] = yp;
    }

    // P_next = (P - g * xP) / lam from live registers (nt stores).
    const float g0 = r0 * inv_den;
    const float g1 = r1 * inv_den;
    const float g2 = r2 * inv_den;
    const float g3 = r3 * inv_den;
    fx4 o;
    o.x = (p0.x - g0 * xq0) * inv_lam;
    o.y = (p0.y - g0 * xq1) * inv_lam;
    o.z = (p0.z - g0 * xq2) * inv_lam;
    o.w = (p0.w - g0 * xq3) * inv_lam;
    __builtin_nontemporal_store(o, &Pnv[256 * w +   0 + l]);
    o.x = (p1.x - g1 * xq0) * inv_lam;
    o.y = (p1.y - g1 * xq1) * inv_lam;
    o.z = (p1.z - g1 * xq2) * inv_lam;
    o.w = (p1.w - g1 * xq3) * inv_lam;
    __builtin_nontemporal_store(o, &Pnv[256 * w +  64 + l]);
    o.x = (p2.x - g2 * xq0) * inv_lam;
    o.y = (p2.y - g2 * xq1) * inv_lam;
    o.z = (p2.z - g2 * xq2) * inv_lam;
    o.w = (p2.w - g2 * xq3) * inv_lam;
    __builtin_nontemporal_store(o, &Pnv[256 * w + 128 + l]);
    o.x = (p3.x - g3 * xq0) * inv_lam;
    o.y = (p3.y - g3 * xq1) * inv_lam;
    o.z = (p3.z - g3 * xq2) * inv_lam;
    o.w = (p3.w - g3 * xq3) * inv_lam;
    __builtin_nontemporal_store(o, &Pnv[256 * w + 192 + l]);
}

extern "C" void kernel_launch(void* const* d_in, const int* in_sizes, int n_in,
                              void* d_out, int out_size, void* d_ws, size_t ws_size,
                              hipStream_t stream) {
    const float* x      = (const float*)d_in[0];
    const float* d      = (const float*)d_in[1];
    const float* w_prev = (const float*)d_in[2];
    const float* P_prev = (const float*)d_in[3];
    const float* ffp    = (const float*)d_in[4];

    const int B = in_sizes[1];   // d has B elements

    float* out    = (float*)d_out;
    float* w_next = out;
    float* P_next = out + (size_t)B * T;
    float* y_hat  = out + (size_t)B * T + (size_t)B * T * T;

    rls_step<<<B, 256, 0, stream>>>(x, d, w_prev, P_prev, ffp,
                                    w_next, P_next, y_hat);
}